// Round 14
// baseline (26.820 us; speedup 1.0000x reference)
//
#include <hip/hip_runtime.h>

// LIF scan, x (B=32,G=4,T=512,C=256) f32 -> 32768 chains, T sequential.
// Memory-bound: 67 MB R + 67 MB W.
//
// R14 = R13's producer/consumer split, halved block span -> full chip.
//  - Block = 128-channel half of sequence n (192 threads = 1 producer wave +
//    2 consumer waves); 256 blocks = 1 block/CU across all 256 CUs (R13 used
//    128). Halves of seq n are blocks b, b+128 -> same XCD automatically.
//  - Producer: global_load_lds_dwordx4, 1 instr = 1 KiB = 2 contiguous rows
//    of the half; 8 instrs/window (16 rows). SIX windows in flight (48 instrs
//    < 63 cap) = 48 KiB/block, 12 MB chip-wide (2x R13). Counted vmcnt(40)
//    steady state - never drains, loads span barriers (T4 discipline).
//  - 8-slot LDS ring (8 x 8 KiB = 64 KiB). Slot safety: W+6 issued after
//    barrier(W) into slot (W-2)%8, last read at iteration W-2.
//  - Consumers: ch = half*128 + wv*64 + lane; stride-1 ds_read (2 lanes/bank,
//    free), free-running scalar stores (store queue never waited).
//  - Recurrence bit-exact: contract off, v=(w*xt)+(a*Vm); Vm'=(Vm-1>=0)?0:v.

constexpr int T_STEPS = 512;
constexpr int CCH     = 256;
constexpr int HCH     = 128;             // channels per block (half)
constexpr int WIN     = 16;              // rows per window
constexpr int K       = 8;               // ring depth (slots)
constexpr int NW      = T_STEPS / WIN;   // 32

__device__ __forceinline__ void sfence() { __builtin_amdgcn_sched_barrier(0); }

__global__ __launch_bounds__(192, 1) void lif_kernel(
    const float* __restrict__ x,
    const float* __restrict__ w_input,
    const float* __restrict__ w_leak,
    float* __restrict__ out)
{
#pragma clang fp contract(off)
    __shared__ float xw[K][WIN * HCH];   // 8 x 8 KiB window ring

    const int tid  = threadIdx.x;
    const int wv   = tid >> 6;           // 0,1 consumers; 2 producer
    const int lane = tid & 63;
    const int b    = blockIdx.x;
    const int n    = b & 127;            // sequence
    const int h    = b >> 7;             // channel half

    const float* xg0 = x + (size_t)n * T_STEPS * CCH + h * HCH;

    if (wv == 2) {
        // ---- producer wave: pure load queue, 6 windows in flight ----
        // lane part: lanes 0-31 cover row r cols 4(lane&31)..+3, lanes 32-63
        // cover row r+1 -> one instr = 1 KiB = rows {r, r+1} of the half.
        const float* xl = xg0 + (lane >> 5) * CCH + (lane & 31) * 4;
        auto issue = [&](int W) {
            const float* s0 = xl + (size_t)W * WIN * CCH;
            float* d0 = &xw[W & 7][0];
#pragma unroll
            for (int i = 0; i < 8; ++i) {
                __builtin_amdgcn_global_load_lds(
                    (const __attribute__((address_space(1))) void*)(s0 + (size_t)(2 * i) * CCH),
                    (__attribute__((address_space(3))) void*)(d0 + i * 256),
                    16, 0, 0);
            }
            sfence();
        };

        issue(0); issue(1); issue(2); issue(3); issue(4); issue(5);
        for (int W = 0; W < NW; ++W) {
            const int rem = NW - 1 - W;
            const int o = rem < 5 ? rem : 5;   // own windows outstanding past W
            if      (o == 5) asm volatile("s_waitcnt vmcnt(40)" ::: "memory");
            else if (o == 4) asm volatile("s_waitcnt vmcnt(32)" ::: "memory");
            else if (o == 3) asm volatile("s_waitcnt vmcnt(24)" ::: "memory");
            else if (o == 2) asm volatile("s_waitcnt vmcnt(16)" ::: "memory");
            else if (o == 1) asm volatile("s_waitcnt vmcnt(8)"  ::: "memory");
            else             asm volatile("s_waitcnt vmcnt(0)"  ::: "memory");
            sfence();
            __builtin_amdgcn_s_barrier();    // window W now readable
            sfence();
            if (W + 6 < NW) issue(W + 6);    // slot (W-2)%8, freed at W-2
        }
    } else {
        // ---- consumer waves: scan + pure store queue ----
        const int cidx = wv * 64 + lane;     // 0..127 within the half
        const int ch   = h * HCH + cidx;
        const float w = w_input[ch];
        const float a = 1.0f - w_leak[ch];
        float* og = out + (size_t)n * T_STEPS * CCH + ch;
        float Vm = 0.0f;

        for (int W = 0; W < NW; ++W) {
            sfence();
            __builtin_amdgcn_s_barrier();    // window W ready in LDS
            sfence();
            const float* xb = &xw[W & 7][0];
#pragma unroll
            for (int k = 0; k < WIN; ++k) {
                const float xt = xb[k * HCH + cidx];     // stride-1, no conflict
                // exact numpy op order: mul, mul, add (no FMA), spike gate
                const float v = (w * xt) + (a * Vm);
                Vm = (Vm - 1.0f >= 0.0f) ? 0.0f : v;
                og[(size_t)(W * WIN + k) * CCH] = Vm;    // free-running store
            }
            sfence();
        }
    }
}

extern "C" void kernel_launch(void* const* d_in, const int* in_sizes, int n_in,
                              void* d_out, int out_size, void* d_ws, size_t ws_size,
                              hipStream_t stream) {
    const float* x       = (const float*)d_in[0];
    const float* w_input = (const float*)d_in[1];
    const float* w_leak  = (const float*)d_in[2];
    float* out = (float*)d_out;

    dim3 grid(256);        // 1 block/CU: 128 sequences x 2 halves
    dim3 block(192);       // 2 consumer waves + 1 producer wave
    hipLaunchKernelGGL(lif_kernel, grid, block, 0, stream,
                       x, w_input, w_leak, out);
}

// Round 15
// 25.595 us; speedup vs baseline: 1.0479x; 1.0479x over previous
//
#include <hip/hip_runtime.h>

// LIF scan, x (B=32,G=4,T=512,C=256) f32 -> 32768 chains, T sequential.
// Memory-bound: 67 MB R + 67 MB W.
//
// R15 = R13 (best, 26.1us) + ONE change: nontemporal consumer stores.
//  Theory: stores allocate in L3 and evict x (64 MB, should fit in 256 MB L3
//  across replays; measured FETCH 33 MB = only half-resident). nt stores
//  stream writes past L3 -> x stays resident -> reads served from L3.
//  - Block = sequence n: 320 threads = 1 producer wave + 4 consumer waves.
//  - Producer: pure global_load_lds_dwordx4 (1 KiB contiguous row per instr)
//    into a K=4-window LDS ring (16 rows/window, 64 KiB). Counted vmcnt(32)
//    per window (W+1,W+2 stay in flight across barriers - T4 discipline).
//  - Consumers: ch = wave*64+lane; scan from LDS (stride-1 ds_read,
//    conflict-free), free-running NONTEMPORAL scalar stores.
//  - Recurrence bit-exact: contract off, v=(w*xt)+(a*Vm); Vm'=(Vm-1>=0)?0:v.

constexpr int T_STEPS = 512;
constexpr int CCH     = 256;
constexpr int NSEQ    = 128;
constexpr int WIN     = 16;              // rows per window
constexpr int K       = 4;               // ring depth (windows)
constexpr int NW      = T_STEPS / WIN;   // 32

__device__ __forceinline__ void sfence() { __builtin_amdgcn_sched_barrier(0); }

__global__ __launch_bounds__(320, 1) void lif_kernel(
    const float* __restrict__ x,
    const float* __restrict__ w_input,
    const float* __restrict__ w_leak,
    float* __restrict__ out)
{
#pragma clang fp contract(off)
    __shared__ float xw[K][WIN * CCH];   // 4 x 16 KiB window ring

    const int tid  = threadIdx.x;
    const int wv   = tid >> 6;           // 0..3 consumers, 4 producer
    const int lane = tid & 63;
    const int n    = blockIdx.x;

    if (wv == 4) {
        // ---- producer wave: pure load queue ----
        const float* xg = x + (size_t)n * T_STEPS * CCH + lane * 4;
        auto issue = [&](int W) {
            const float* s0 = xg + (size_t)W * WIN * CCH;
            float* d0 = &xw[W & 3][0];
#pragma unroll
            for (int i = 0; i < WIN; ++i) {
                // one instr = one contiguous 1 KiB row t = W*16+i
                __builtin_amdgcn_global_load_lds(
                    (const __attribute__((address_space(1))) void*)(s0 + i * CCH),
                    (__attribute__((address_space(3))) void*)(d0 + i * CCH),
                    16, 0, 0);
            }
            sfence();
        };

        issue(0); issue(1); issue(2);    // 48 outstanding (< 63 cap)
        for (int W = 0; W < NW; ++W) {
            const int rem = NW - 1 - W;  // windows still outstanding after W
            if (rem >= 2)      asm volatile("s_waitcnt vmcnt(32)" ::: "memory");
            else if (rem == 1) asm volatile("s_waitcnt vmcnt(16)" ::: "memory");
            else               asm volatile("s_waitcnt vmcnt(0)"  ::: "memory");
            sfence();
            __builtin_amdgcn_s_barrier();   // window W now readable
            sfence();
            if (W + 3 < NW) issue(W + 3);   // into slot consumers freed at W-1
        }
    } else {
        // ---- consumer waves: scan + pure store queue (nontemporal) ----
        const int ch = wv * 64 + lane;
        const float w = w_input[ch];
        const float a = 1.0f - w_leak[ch];
        float* og = out + (size_t)n * T_STEPS * CCH + ch;
        float Vm = 0.0f;

        for (int W = 0; W < NW; ++W) {
            sfence();
            __builtin_amdgcn_s_barrier();   // window W ready in LDS
            sfence();
            const float* xb = &xw[W & 3][0];
#pragma unroll
            for (int k = 0; k < WIN; ++k) {
                const float xt = xb[k * CCH + ch];       // stride-1, no conflict
                // exact numpy op order: mul, mul, add (no FMA), spike gate
                const float v = (w * xt) + (a * Vm);
                Vm = (Vm - 1.0f >= 0.0f) ? 0.0f : v;
                __builtin_nontemporal_store(
                    Vm, og + (size_t)(W * WIN + k) * CCH);  // stream past L3
            }
            sfence();
        }
    }
}

extern "C" void kernel_launch(void* const* d_in, const int* in_sizes, int n_in,
                              void* d_out, int out_size, void* d_ws, size_t ws_size,
                              hipStream_t stream) {
    const float* x       = (const float*)d_in[0];
    const float* w_input = (const float*)d_in[1];
    const float* w_leak  = (const float*)d_in[2];
    float* out = (float*)d_out;

    dim3 grid(NSEQ);       // 128 blocks, block n = sequence n
    dim3 block(320);       // 4 consumer waves + 1 producer wave
    hipLaunchKernelGGL(lif_kernel, grid, block, 0, stream,
                       x, w_input, w_leak, out);
}